// Round 1
// baseline (624.078 us; speedup 1.0000x reference)
//
#include <hip/hip_runtime.h>
#include <cstdint>
#include <cstddef>

#define B_ 8
#define S_ 4096
#define D_ 2048
#define N_ 8192
#define K_ 64
#define CH_ 64          // number of s-chunks for partial query sums
#define SC_ 64          // S_ / CH_
#define NEG_INF (-3.402823466e+38f)

// ---------------- helpers ----------------
__device__ inline float wave_reduce_sum(float v) {
#pragma unroll
    for (int off = 32; off > 0; off >>= 1) v += __shfl_down(v, off, 64);
    return v;
}

// ---------------- Kernel A: copy x -> out, partial masked sums over s-chunks
// grid: B_ * 2 * CH_ = 1024 blocks, 256 threads
__global__ __launch_bounds__(256) void kA(const float* __restrict__ x,
                                          const unsigned char* __restrict__ mask,
                                          float* __restrict__ out,
                                          float* __restrict__ part) {
    const int bi   = blockIdx.x;
    const int c    = bi & (CH_ - 1);
    const int half = (bi >> 6) & 1;
    const int b    = bi >> 7;
    const int t    = threadIdx.x;
    const int f4   = half * 256 + t;          // 0..511 (float4 index within D)

    const float4* x4  = (const float4*)x;
    float4*       o4  = (float4*)out;
    const unsigned char* mrow = mask + b * S_;

    float4 acc = make_float4(0.f, 0.f, 0.f, 0.f);
    const int s0 = c * SC_;
#pragma unroll 4
    for (int s = s0; s < s0 + SC_; ++s) {
        const int idx = (b * S_ + s) * 512 + f4;
        float4 v = x4[idx];
        o4[idx] = v;
        if (mrow[s]) { acc.x += v.x; acc.y += v.y; acc.z += v.z; acc.w += v.w; }
    }
    ((float4*)part)[(b * CH_ + c) * 512 + f4] = acc;
}

// ---------------- Kernel A2: reduce partials -> qsum[b][d]
// grid: 64 blocks (b*8+dg), 256 threads
__global__ __launch_bounds__(256) void kA2(const float* __restrict__ part,
                                           float* __restrict__ qsum) {
    const int b  = blockIdx.x >> 3;
    const int dg = blockIdx.x & 7;
    const int d  = dg * 256 + threadIdx.x;
    float acc = 0.f;
#pragma unroll 8
    for (int c = 0; c < CH_; ++c) acc += part[(b * CH_ + c) * D_ + d];
    qsum[b * D_ + d] = acc;
}

// ---------------- Kernel A3: qn[b] = max(||qsum_b||, eps); last[b]
// grid: 8 blocks, 256 threads
__global__ __launch_bounds__(256) void kA3(const float* __restrict__ qsum,
                                           const unsigned char* __restrict__ mask,
                                           float* __restrict__ qn,
                                           int* __restrict__ lastI) {
    const int b = blockIdx.x;
    const int t = threadIdx.x;
    float sq = 0.f;
#pragma unroll
    for (int j = 0; j < 8; ++j) {
        float v = qsum[b * D_ + j * 256 + t];
        sq = fmaf(v, v, sq);
    }
    float fcnt = 0.f;
#pragma unroll
    for (int j = 0; j < 16; ++j)
        fcnt += (mask[b * S_ + j * 256 + t] != 0) ? 1.0f : 0.0f;

    sq   = wave_reduce_sum(sq);
    fcnt = wave_reduce_sum(fcnt);

    __shared__ float sv[4];
    __shared__ float sc[4];
    const int w = t >> 6, lane = t & 63;
    if (lane == 0) { sv[w] = sq; sc[w] = fcnt; }
    __syncthreads();
    if (t == 0) {
        float s = sv[0] + sv[1] + sv[2] + sv[3];
        int   c = (int)(sc[0] + sc[1] + sc[2] + sc[3] + 0.5f);
        qn[b]    = fmaxf(sqrtf(s), 1e-12f);
        lastI[b] = (c > 1 ? c : 1) - 1;
    }
}

// ---------------- Kernel B: sims[b][n] = dot(qsum_b, key_n) / (qn_b * kn_n)
// grid: 512 blocks, 256 threads (4 waves), each wave does 4 key rows
__global__ __launch_bounds__(256) void kB(const float* __restrict__ keys,
                                          const float* __restrict__ qsum,
                                          const float* __restrict__ qn,
                                          float* __restrict__ sims) {
    __shared__ float qs[B_ * D_];      // 64 KB, b-major: qs[b*D_ + d]
    const int t = threadIdx.x;
    {
        const float4* g4 = (const float4*)qsum;
        float4*       l4 = (float4*)qs;
#pragma unroll
        for (int j = 0; j < 16; ++j) l4[j * 256 + t] = g4[j * 256 + t];
    }
    __syncthreads();

    const int wv = t >> 6, lane = t & 63;
    const float4* k4  = (const float4*)keys;
    const float4* q4  = (const float4*)qs;

    for (int r = 0; r < 4; ++r) {
        const int row = blockIdx.x * 16 + wv * 4 + r;
        float kk = 0.f;
        float dots[8];
#pragma unroll
        for (int i = 0; i < 8; ++i) dots[i] = 0.f;

#pragma unroll
        for (int seg = 0; seg < 8; ++seg) {
            float4 kv = k4[row * 512 + seg * 64 + lane];
            kk = fmaf(kv.x, kv.x, kk);
            kk = fmaf(kv.y, kv.y, kk);
            kk = fmaf(kv.z, kv.z, kk);
            kk = fmaf(kv.w, kv.w, kk);
#pragma unroll
            for (int b = 0; b < 8; ++b) {
                float4 q = q4[b * 512 + seg * 64 + lane];   // lane-consecutive b128: conflict-free
                dots[b] = fmaf(kv.x, q.x,
                          fmaf(kv.y, q.y,
                          fmaf(kv.z, q.z,
                          fmaf(kv.w, q.w, dots[b]))));
            }
        }
        // wave reduction (9 scalars)
#pragma unroll
        for (int off = 32; off > 0; off >>= 1) {
            kk += __shfl_down(kk, off, 64);
#pragma unroll
            for (int i = 0; i < 8; ++i) dots[i] += __shfl_down(dots[i], off, 64);
        }
        if (lane == 0) {
            float invk = 1.0f / fmaxf(sqrtf(kk), 1e-12f);
#pragma unroll
            for (int i = 0; i < 8; ++i)
                sims[i * N_ + row] = dots[i] * invk / qn[i];
        }
    }
}

// ---------------- Kernel C: exact top-64 per row + softmax + gate -> cw, cidx
// grid: 8 blocks (one per b), 256 threads
__global__ __launch_bounds__(256) void kC(const float* __restrict__ sims,
                                          float* __restrict__ cw,
                                          int* __restrict__ cidx) {
    const int b = blockIdx.x;
    const int t = threadIdx.x;
    const int w = t >> 6, lane = t & 63;

    float v[32];
#pragma unroll
    for (int j = 0; j < 32; ++j) v[j] = sims[b * N_ + j * 256 + t];

    __shared__ float tv[64];
    __shared__ int   ti[64];
    __shared__ float rv[4];
    __shared__ int   ri[4];

    for (int k = 0; k < K_; ++k) {
        // local argmax over 32 registers
        float lv = NEG_INF;
        int   li = 0;
#pragma unroll
        for (int j = 0; j < 32; ++j) {
            if (v[j] > lv) { lv = v[j]; li = j; }
        }
        int gi = li * 256 + t;
        // wave argmax
#pragma unroll
        for (int off = 32; off > 0; off >>= 1) {
            float ov = __shfl_down(lv, off, 64);
            int   oi = __shfl_down(gi, off, 64);
            if (ov > lv) { lv = ov; gi = oi; }
        }
        if (lane == 0) { rv[w] = lv; ri[w] = gi; }
        __syncthreads();
        if (t == 0) {
            float bv = rv[0]; int bi2 = ri[0];
#pragma unroll
            for (int q = 1; q < 4; ++q)
                if (rv[q] > bv) { bv = rv[q]; bi2 = ri[q]; }
            tv[k] = bv; ti[k] = bi2;
        }
        __syncthreads();
        const int win = ti[k];
        if ((win & 255) == t) {
            const int jj = win >> 8;
#pragma unroll
            for (int j = 0; j < 32; ++j)
                if (j == jj) v[j] = NEG_INF;
        }
        __syncthreads();
    }

    if (t < 64) {
        const float vmax = tv[0];
        float wgt = expf((tv[t] - vmax) * (1.0f / 0.03f));
        float z = wgt;
#pragma unroll
        for (int off = 32; off > 0; off >>= 1) z += __shfl_down(z, off, 64);
        z = __shfl(z, 0, 64);
        const float gate = 1.0f / (1.0f + expf(-(vmax - 0.85f) * 40.0f));
        const float coef = 16.0f * gate / z;
        cw[b * 64 + t]   = coef * wgt;
        cidx[b * 64 + t] = ti[t];
    }
}

// ---------------- Kernel D: out[b, last, :] += sum_i cw_i * values[idx_i, :]
// grid: 8 blocks, 256 threads
__global__ __launch_bounds__(256) void kD(const float* __restrict__ values,
                                          const float* __restrict__ cw,
                                          const int* __restrict__ cidx,
                                          const int* __restrict__ lastI,
                                          float* __restrict__ out) {
    const int b = blockIdx.x;
    const int t = threadIdx.x;
    const float4* v4 = (const float4*)values;
    float4 a0 = make_float4(0.f, 0.f, 0.f, 0.f);
    float4 a1 = make_float4(0.f, 0.f, 0.f, 0.f);
#pragma unroll 4
    for (int i = 0; i < K_; ++i) {
        const float wgt = cw[b * 64 + i];
        const int   n   = cidx[b * 64 + i];
        const float4* r = v4 + (size_t)n * 512;
        float4 x0 = r[t], x1 = r[256 + t];
        a0.x = fmaf(wgt, x0.x, a0.x); a0.y = fmaf(wgt, x0.y, a0.y);
        a0.z = fmaf(wgt, x0.z, a0.z); a0.w = fmaf(wgt, x0.w, a0.w);
        a1.x = fmaf(wgt, x1.x, a1.x); a1.y = fmaf(wgt, x1.y, a1.y);
        a1.z = fmaf(wgt, x1.z, a1.z); a1.w = fmaf(wgt, x1.w, a1.w);
    }
    const int last = lastI[b];
    float4* o4 = (float4*)out + ((size_t)(b * S_ + last)) * 512;
    float4 c0 = o4[t], c1 = o4[256 + t];
    c0.x += a0.x; c0.y += a0.y; c0.z += a0.z; c0.w += a0.w;
    c1.x += a1.x; c1.y += a1.y; c1.z += a1.z; c1.w += a1.w;
    o4[t] = c0;
    o4[256 + t] = c1;
}

// ---------------- launcher ----------------
extern "C" void kernel_launch(void* const* d_in, const int* in_sizes, int n_in,
                              void* d_out, int out_size, void* d_ws, size_t ws_size,
                              hipStream_t stream) {
    const float*         x      = (const float*)d_in[0];
    const unsigned char* mask   = (const unsigned char*)d_in[1];
    const float*         keys   = (const float*)d_in[2];
    const float*         values = (const float*)d_in[3];
    float*               out    = (float*)d_out;

    char* ws = (char*)d_ws;
    // workspace layout (all 16B-aligned)
    float* part = (float*)(ws);                       // B*CH*D        = 4 MB
    float* qsum = (float*)(ws + 4194304);             // B*D           = 64 KB
    float* qn   = (float*)(ws + 4259840);             // B             = 32 B
    int*   last = (int*)  (ws + 4259872);             // B             = 32 B
    float* sims = (float*)(ws + 4259904);             // B*N           = 256 KB
    float* cw   = (float*)(ws + 4522048);             // B*K           = 2 KB
    int*   cidx = (int*)  (ws + 4524096);             // B*K           = 2 KB

    kA <<<dim3(B_ * 2 * CH_), dim3(256), 0, stream>>>(x, mask, out, part);
    kA2<<<dim3(64),           dim3(256), 0, stream>>>(part, qsum);
    kA3<<<dim3(B_),           dim3(256), 0, stream>>>(qsum, mask, qn, last);
    kB <<<dim3(N_ / 16),      dim3(256), 0, stream>>>(keys, qsum, qn, sims);
    kC <<<dim3(B_),           dim3(256), 0, stream>>>(sims, cw, cidx);
    kD <<<dim3(B_),           dim3(256), 0, stream>>>(values, cw, cidx, last, out);
}